// Round 1
// baseline (286.510 us; speedup 1.0000x reference)
//
#include <hip/hip_runtime.h>

#define LOG2E 1.4426950408889634f

__device__ __forceinline__ float bcastf(float v, int lane) {
    return __uint_as_float(__builtin_amdgcn_readlane(__float_as_uint(v), lane));
}

// ---------------------------------------------------------------------------
// Kernel 1: 2-layer LSTM (H=16) over the single batch element that matters
// (b = 4095). One wave, lane j owns gate j (i:0-15, f:16-31, g:32-47, o:48-63).
// Layer 2 runs one step behind layer 1 in the same loop so the two dependency
// chains overlap. h2[t] (16 floats) streamed to global (d_ws).
// ---------------------------------------------------------------------------
__global__ __launch_bounds__(64) void lstm2_kernel(
    const float* __restrict__ x,
    const float* __restrict__ Wih0, const float* __restrict__ Whh0,
    const float* __restrict__ bih0, const float* __restrict__ bhh0,
    const float* __restrict__ Wih1, const float* __restrict__ Whh1,
    const float* __restrict__ bih1, const float* __restrict__ bhh1,
    float* __restrict__ h2out)
{
    const int j = threadIdx.x;      // 0..63
    const int m = j & 15;

    // Stage x[t, 4095, 0] for all t into LDS (uncoalesced gather, once).
    __shared__ float xs[512];
    for (int i = j; i < 512; i += 64)
        xs[i] = x[i * 4096 + 4095];
    __syncthreads();

    // Per-lane weights (row j of each 64x16 matrix).
    float whh0[16], wih1[16], whh1[16];
    #pragma unroll
    for (int k = 0; k < 16; ++k) {
        whh0[k] = Whh0[j * 16 + k];
        wih1[k] = Wih1[j * 16 + k];
        whh1[k] = Whh1[j * 16 + k];
    }
    const float wih0  = Wih0[j];
    const float bias0 = bih0[j] + bhh0[j];
    const float bias1 = bih1[j] + bhh1[j];

    // Branchless activation: lanes 32..47 need tanh = 2*sigmoid(2x)-1,
    // others sigmoid. Fold into per-lane constants.
    const bool  isg = (j >= 32 && j < 48);
    const float am  = isg ? (-2.0f * LOG2E) : (-LOG2E); // exp2 multiplier
    const float aa  = isg ?  2.0f : 1.0f;
    const float ac  = isg ? -1.0f : 0.0f;

    float h1 = 0.f, c1 = 0.f, h2 = 0.f, c2 = 0.f;

    for (int t = 0; t <= 512; ++t) {
        const float xt = (t < 512) ? xs[t] : 0.f;

        // Broadcast h1[t-1] and h2[t-2] (replicated: lane k holds h[k&15]).
        float s1[16], s2[16];
        #pragma unroll
        for (int k = 0; k < 16; ++k) { s1[k] = bcastf(h1, k); }
        #pragma unroll
        for (int k = 0; k < 16; ++k) { s2[k] = bcastf(h2, k); }

        // Layer-1 gate j: Wih0[j]*x_t + bias + Whh0[j,:].h1   (4-accum tree)
        float a0 = fmaf(whh0[0], s1[0], fmaf(wih0, xt, bias0));
        float a1 = whh0[1] * s1[1];
        float a2 = whh0[2] * s1[2];
        float a3 = whh0[3] * s1[3];
        #pragma unroll
        for (int k = 4; k < 16; k += 4) {
            a0 = fmaf(whh0[k + 0], s1[k + 0], a0);
            a1 = fmaf(whh0[k + 1], s1[k + 1], a1);
            a2 = fmaf(whh0[k + 2], s1[k + 2], a2);
            a3 = fmaf(whh0[k + 3], s1[k + 3], a3);
        }
        const float ga = (a0 + a1) + (a2 + a3);

        // Layer-2 gate j: Wih1[j,:].h1[t-1] + bias + Whh1[j,:].h2[t-2]
        float b0 = fmaf(wih1[0], s1[0], bias1);
        float b1v = wih1[1] * s1[1];
        float b2v = wih1[2] * s1[2];
        float b3v = wih1[3] * s1[3];
        #pragma unroll
        for (int k = 4; k < 16; k += 4) {
            b0  = fmaf(wih1[k + 0], s1[k + 0], b0);
            b1v = fmaf(wih1[k + 1], s1[k + 1], b1v);
            b2v = fmaf(wih1[k + 2], s1[k + 2], b2v);
            b3v = fmaf(wih1[k + 3], s1[k + 3], b3v);
        }
        #pragma unroll
        for (int k = 0; k < 16; k += 4) {
            b0  = fmaf(whh1[k + 0], s2[k + 0], b0);
            b1v = fmaf(whh1[k + 1], s2[k + 1], b1v);
            b2v = fmaf(whh1[k + 2], s2[k + 2], b2v);
            b3v = fmaf(whh1[k + 3], s2[k + 3], b3v);
        }
        const float gb = (b0 + b1v) + (b2v + b3v);

        // Activations (branchless, one exp2+rcp per gate).
        const float ea   = __builtin_amdgcn_exp2f(am * ga);
        const float acta = fmaf(aa, __builtin_amdgcn_rcpf(1.0f + ea), ac);
        const float eb   = __builtin_amdgcn_exp2f(am * gb);
        const float actb = fmaf(aa, __builtin_amdgcn_rcpf(1.0f + eb), ac);

        // Gather i,f,g,o for cell index m = j&15 (all lanes replicate).
        const float i1 = __shfl(acta, m);
        const float f1 = __shfl(acta, m + 16);
        const float g1 = __shfl(acta, m + 32);
        const float o1 = __shfl(acta, m + 48);
        const float i2 = __shfl(actb, m);
        const float f2 = __shfl(actb, m + 16);
        const float g2 = __shfl(actb, m + 32);
        const float o2 = __shfl(actb, m + 48);

        // Layer-1 cell update (only while t < 512).
        if (t < 512) {
            c1 = fmaf(f1, c1, i1 * g1);
            const float e1 = __builtin_amdgcn_exp2f(-2.0f * LOG2E * c1);
            const float th1 = fmaf(2.0f, __builtin_amdgcn_rcpf(1.0f + e1), -1.0f);
            h1 = o1 * th1;
        }
        // Layer-2 cell update for step t-1 (skip the bogus t=0 iteration).
        if (t > 0) {
            c2 = fmaf(f2, c2, i2 * g2);
            const float e2 = __builtin_amdgcn_exp2f(-2.0f * LOG2E * c2);
            const float th2 = fmaf(2.0f, __builtin_amdgcn_rcpf(1.0f + e2), -1.0f);
            h2 = o2 * th2;
            if (j < 16) h2out[(t - 1) * 16 + j] = h2;
        }
    }
}

// ---------------------------------------------------------------------------
// Kernel 2: per-timestep MLP 16 -> 64 -> 32 -> 1 on the 512 h2 rows.
// One thread per row; weights are same-address broadcast loads (L1-resident).
// ---------------------------------------------------------------------------
__global__ __launch_bounds__(64) void mlp_kernel(
    const float* __restrict__ h2g,
    const float* __restrict__ W1, const float* __restrict__ b1,
    const float* __restrict__ W2, const float* __restrict__ b2,
    const float* __restrict__ W3, const float* __restrict__ b3,
    float* __restrict__ out)
{
    const int r = blockIdx.x * 64 + threadIdx.x;   // 0..511

    float h[16];
    #pragma unroll
    for (int q = 0; q < 4; ++q) {
        const float4 v = reinterpret_cast<const float4*>(h2g + r * 16)[q];
        h[4 * q + 0] = v.x; h[4 * q + 1] = v.y;
        h[4 * q + 2] = v.z; h[4 * q + 3] = v.w;
    }

    float a1[64];
    #pragma unroll
    for (int u = 0; u < 64; ++u) {
        const float4* wr = reinterpret_cast<const float4*>(W1 + u * 16);
        float s = b1[u];
        #pragma unroll
        for (int q = 0; q < 4; ++q) {
            const float4 w = wr[q];
            s = fmaf(w.x, h[4 * q + 0], s);
            s = fmaf(w.y, h[4 * q + 1], s);
            s = fmaf(w.z, h[4 * q + 2], s);
            s = fmaf(w.w, h[4 * q + 3], s);
        }
        a1[u] = fmaxf(s, 0.0f);
    }

    float o = b3[0];
    #pragma unroll
    for (int v = 0; v < 32; ++v) {
        const float4* wr = reinterpret_cast<const float4*>(W2 + v * 64);
        float s = b2[v];
        #pragma unroll
        for (int q = 0; q < 16; ++q) {
            const float4 w = wr[q];
            s = fmaf(w.x, a1[4 * q + 0], s);
            s = fmaf(w.y, a1[4 * q + 1], s);
            s = fmaf(w.z, a1[4 * q + 2], s);
            s = fmaf(w.w, a1[4 * q + 3], s);
        }
        o = fmaf(fmaxf(s, 0.0f), W3[v], o);
    }
    out[r] = o;
}

extern "C" void kernel_launch(void* const* d_in, const int* in_sizes, int n_in,
                              void* d_out, int out_size, void* d_ws, size_t ws_size,
                              hipStream_t stream) {
    const float* x    = (const float*)d_in[0];
    const float* Wih0 = (const float*)d_in[1];
    const float* Whh0 = (const float*)d_in[2];
    const float* bih0 = (const float*)d_in[3];
    const float* bhh0 = (const float*)d_in[4];
    const float* Wih1 = (const float*)d_in[5];
    const float* Whh1 = (const float*)d_in[6];
    const float* bih1 = (const float*)d_in[7];
    const float* bhh1 = (const float*)d_in[8];
    const float* W1   = (const float*)d_in[9];
    const float* b1   = (const float*)d_in[10];
    const float* W2   = (const float*)d_in[11];
    const float* b2   = (const float*)d_in[12];
    const float* W3   = (const float*)d_in[13];
    const float* b3   = (const float*)d_in[14];

    float* h2g = (float*)d_ws;          // 512 * 16 floats = 32 KiB scratch
    float* out = (float*)d_out;         // 512 floats

    hipLaunchKernelGGL(lstm2_kernel, dim3(1), dim3(64), 0, stream,
                       x, Wih0, Whh0, bih0, bhh0, Wih1, Whh1, bih1, bhh1, h2g);
    hipLaunchKernelGGL(mlp_kernel, dim3(8), dim3(64), 0, stream,
                       h2g, W1, b1, W2, b2, W3, b3, out);
}

// Round 2
// 232.890 us; speedup vs baseline: 1.2302x; 1.2302x over previous
//
#include <hip/hip_runtime.h>

#define LOG2E 1.4426950408889634f

__device__ __forceinline__ float bcastf(float v, int lane) {
    return __uint_as_float(__builtin_amdgcn_readlane(__float_as_uint(v), lane));
}

// Quad broadcast via DPP quad_perm (ctrl 0x00/0x55/0xAA/0xFF = bcast lane 0/1/2/3 of quad)
template<int CTRL>
__device__ __forceinline__ float qb(float v) {
    return __uint_as_float(__builtin_amdgcn_update_dpp(
        0, __float_as_uint(v), CTRL, 0xF, 0xF, true));
}

// sigmoid / scaled-tanh from pre-scaled gate input p (already multiplied by -log2e / -2log2e)
__device__ __forceinline__ float gate_act(float p, float aa, float ac) {
    const float e = __builtin_amdgcn_exp2f(p);
    const float r = __builtin_amdgcn_rcpf(1.0f + e);
    return fmaf(aa, r, ac);
}

// Gather i/f/g/o within the quad and do the cell update.
// cs is the scaled cell state K*c (K = -2*log2e); the g-gate act is pre-scaled by K,
// so cs_new = f*cs + i*(K*g) and tanh(c) = 2*rcp(1+exp2(cs)) - 1 directly.
__device__ __forceinline__ void cell_update(float act, float& cs, float& h) {
    const float iv = qb<0x00>(act);
    const float fv = qb<0x55>(act);
    const float gv = qb<0xAA>(act);   // = K * tanh(gate_g)
    const float ov = qb<0xFF>(act);
    cs = fmaf(fv, cs, iv * gv);
    const float e  = __builtin_amdgcn_exp2f(cs);
    const float th = fmaf(2.0f, __builtin_amdgcn_rcpf(1.0f + e), -1.0f);
    h = ov * th;
}

// 16-term dot with 4 accumulator chains (depth 4)
__device__ __forceinline__ float dot16(const float* __restrict__ w,
                                       const float* __restrict__ s, float seed) {
    float a0 = fmaf(w[0], s[0], seed);
    float a1 = w[1] * s[1];
    float a2 = w[2] * s[2];
    float a3 = w[3] * s[3];
    #pragma unroll
    for (int k = 4; k < 16; k += 4) {
        a0 = fmaf(w[k + 0], s[k + 0], a0);
        a1 = fmaf(w[k + 1], s[k + 1], a1);
        a2 = fmaf(w[k + 2], s[k + 2], a2);
        a3 = fmaf(w[k + 3], s[k + 3], a3);
    }
    return (a0 + a1) + (a2 + a3);
}

// 32-term dot (two 16-vectors) with 4 accumulator chains (depth 8)
__device__ __forceinline__ float dot16x2(const float* __restrict__ wa, const float* __restrict__ sa,
                                         const float* __restrict__ wb, const float* __restrict__ sb,
                                         float seed) {
    float a0 = fmaf(wa[0], sa[0], seed);
    float a1 = wa[1] * sa[1];
    float a2 = wa[2] * sa[2];
    float a3 = wa[3] * sa[3];
    #pragma unroll
    for (int k = 4; k < 16; k += 4) {
        a0 = fmaf(wa[k + 0], sa[k + 0], a0);
        a1 = fmaf(wa[k + 1], sa[k + 1], a1);
        a2 = fmaf(wa[k + 2], sa[k + 2], a2);
        a3 = fmaf(wa[k + 3], sa[k + 3], a3);
    }
    #pragma unroll
    for (int k = 0; k < 16; k += 4) {
        a0 = fmaf(wb[k + 0], sb[k + 0], a0);
        a1 = fmaf(wb[k + 1], sb[k + 1], a1);
        a2 = fmaf(wb[k + 2], sb[k + 2], a2);
        a3 = fmaf(wb[k + 3], sb[k + 3], a3);
    }
    return (a0 + a1) + (a2 + a3);
}

// ---------------------------------------------------------------------------
// Fused kernel, one block of 512 threads.
// Phase 1 (wave 0 only): 2-layer LSTM (H=16) on batch element 4095.
//   Lane layout: lane = 4*m + g, m = cell (0..15), g = gate (0=i,1=f,2=g,3=o).
//   Weight row in the original matrices: row = g*16 + m.
//   Weights/biases pre-scaled by -log2e (i,f,o) / -2log2e (g) so exp2 consumes
//   the raw FMA result. g-gate activation additionally scaled by K = -2log2e
//   so the cell-state recurrence stays in exp2 domain.
//   Layer 2 runs one step behind layer 1 (chains overlap as ILP).
//   h2 rows go to LDS.
// Phase 2 (all 512 threads): per-timestep MLP 16->64->32->1, one row/thread.
// ---------------------------------------------------------------------------
__global__ __launch_bounds__(512) void lstm_fused_kernel(
    const float* __restrict__ x,
    const float* __restrict__ Wih0, const float* __restrict__ Whh0,
    const float* __restrict__ bih0, const float* __restrict__ bhh0,
    const float* __restrict__ Wih1, const float* __restrict__ Whh1,
    const float* __restrict__ bih1, const float* __restrict__ bhh1,
    const float* __restrict__ W1, const float* __restrict__ b1,
    const float* __restrict__ W2, const float* __restrict__ b2,
    const float* __restrict__ W3, const float* __restrict__ b3,
    float* __restrict__ out)
{
    const int tid = threadIdx.x;

    __shared__ float xs[513];
    __shared__ float h2s[512 * 16];

    // Stage x[t, 4095, 0] (uncoalesced gather, once, all waves help).
    xs[tid] = x[tid * 4096 + 4095];
    if (tid == 0) xs[512] = 0.0f;
    __syncthreads();

    if (tid < 64) {
        const int j = tid;
        const int m = j >> 2;
        const int g = j & 3;
        const int row = g * 16 + m;

        const float K  = -2.0f * LOG2E;
        const float sc = (g == 2) ? K : -LOG2E;

        float whh0[16], wih1[16], whh1[16];
        #pragma unroll
        for (int k = 0; k < 16; ++k) {
            whh0[k] = Whh0[row * 16 + k] * sc;
            wih1[k] = Wih1[row * 16 + k] * sc;
            whh1[k] = Whh1[row * 16 + k] * sc;
        }
        const float wx0   = Wih0[row] * sc;
        const float bias0 = (bih0[row] + bhh0[row]) * sc;
        const float bias1 = (bih1[row] + bhh1[row]) * sc;

        // act = aa * rcp(1+exp2(p)) + ac : sigmoid for i/f/o; K*tanh for g-gate.
        const float aa = (g == 2) ? (2.0f * K) : 1.0f;
        const float ac = (g == 2) ? (-K)       : 0.0f;

        float h1 = 0.0f, c1s = 0.0f, h2 = 0.0f, c2s = 0.0f;

        // ---- peeled t = 0: layer 1 only (h1 == 0 so recurrent term vanishes)
        {
            const float p = fmaf(wx0, xs[0], bias0);
            cell_update(gate_act(p, aa, ac), c1s, h1);
        }

        // ---- main loop: layer-1 step t, layer-2 step t-1
        float xcur = xs[1];
        for (int t = 1; t < 512; ++t) {
            const float xnext = xs[t + 1];   // prefetch (xs[512] = 0 pad)

            float s1[16], s2[16];
            #pragma unroll
            for (int k = 0; k < 16; ++k) s1[k] = bcastf(h1, 4 * k);
            #pragma unroll
            for (int k = 0; k < 16; ++k) s2[k] = bcastf(h2, 4 * k);

            const float p1 = dot16(whh0, s1, fmaf(wx0, xcur, bias0));
            const float p2 = dot16x2(wih1, s1, whh1, s2, bias1);

            const float act1 = gate_act(p1, aa, ac);
            const float act2 = gate_act(p2, aa, ac);

            cell_update(act1, c1s, h1);
            cell_update(act2, c2s, h2);

            if (g == 0) h2s[(t - 1) * 16 + m] = h2;
            xcur = xnext;
        }

        // ---- peeled tail: layer-2 step 511
        {
            float s1[16], s2[16];
            #pragma unroll
            for (int k = 0; k < 16; ++k) s1[k] = bcastf(h1, 4 * k);
            #pragma unroll
            for (int k = 0; k < 16; ++k) s2[k] = bcastf(h2, 4 * k);
            const float p2 = dot16x2(wih1, s1, whh1, s2, bias1);
            cell_update(gate_act(p2, aa, ac), c2s, h2);
            if (g == 0) h2s[511 * 16 + m] = h2;
        }
    }

    __syncthreads();

    // ---- Phase 2: MLP, one timestep row per thread --------------------------
    const int r = tid;

    float h[16];
    #pragma unroll
    for (int q = 0; q < 4; ++q) {
        const float4 v = reinterpret_cast<const float4*>(&h2s[r * 16])[q];
        h[4 * q + 0] = v.x; h[4 * q + 1] = v.y;
        h[4 * q + 2] = v.z; h[4 * q + 3] = v.w;
    }

    float a1[64];
    #pragma unroll
    for (int u = 0; u < 64; ++u) {
        const float4* wr = reinterpret_cast<const float4*>(W1 + u * 16);
        float s = b1[u];
        #pragma unroll
        for (int q = 0; q < 4; ++q) {
            const float4 w = wr[q];
            s = fmaf(w.x, h[4 * q + 0], s);
            s = fmaf(w.y, h[4 * q + 1], s);
            s = fmaf(w.z, h[4 * q + 2], s);
            s = fmaf(w.w, h[4 * q + 3], s);
        }
        a1[u] = fmaxf(s, 0.0f);
    }

    float o = b3[0];
    #pragma unroll
    for (int v = 0; v < 32; ++v) {
        const float4* wr = reinterpret_cast<const float4*>(W2 + v * 64);
        float s = b2[v];
        #pragma unroll
        for (int q = 0; q < 16; ++q) {
            const float4 w = wr[q];
            s = fmaf(w.x, a1[4 * q + 0], s);
            s = fmaf(w.y, a1[4 * q + 1], s);
            s = fmaf(w.z, a1[4 * q + 2], s);
            s = fmaf(w.w, a1[4 * q + 3], s);
        }
        o = fmaf(fmaxf(s, 0.0f), W3[v], o);
    }
    out[r] = o;
}

extern "C" void kernel_launch(void* const* d_in, const int* in_sizes, int n_in,
                              void* d_out, int out_size, void* d_ws, size_t ws_size,
                              hipStream_t stream) {
    const float* x    = (const float*)d_in[0];
    const float* Wih0 = (const float*)d_in[1];
    const float* Whh0 = (const float*)d_in[2];
    const float* bih0 = (const float*)d_in[3];
    const float* bhh0 = (const float*)d_in[4];
    const float* Wih1 = (const float*)d_in[5];
    const float* Whh1 = (const float*)d_in[6];
    const float* bih1 = (const float*)d_in[7];
    const float* bhh1 = (const float*)d_in[8];
    const float* W1   = (const float*)d_in[9];
    const float* b1   = (const float*)d_in[10];
    const float* W2   = (const float*)d_in[11];
    const float* b2   = (const float*)d_in[12];
    const float* W3   = (const float*)d_in[13];
    const float* b3   = (const float*)d_in[14];

    hipLaunchKernelGGL(lstm_fused_kernel, dim3(1), dim3(512), 0, stream,
                       x, Wih0, Whh0, bih0, bhh0, Wih1, Whh1, bih1, bhh1,
                       W1, b1, W2, b2, W3, b3, (float*)d_out);
}